// Round 3
// baseline (474.716 us; speedup 1.0000x reference)
//
#include <hip/hip_runtime.h>
#include <math.h>

#define BB   8192
#define NIN  1433
#define NH   64
#define SUBG 6
#define HID  128

#define KC_G 45      // ceil(1433/32) k-chunks for GCN

typedef __attribute__((ext_vector_type(8))) short bf16x8;
typedef __attribute__((ext_vector_type(4))) float f32x4;

__device__ __forceinline__ short f2bf(float x) {
  unsigned u = __float_as_uint(x);
  unsigned r = (u + 0x7fffu + ((u >> 16) & 1u)) >> 16;   // RNE
  return (short)r;
}
__device__ __forceinline__ float bf2f(short s) {
  return __uint_as_float(((unsigned)(unsigned short)s) << 16);
}
__device__ __forceinline__ float allred64(float v) {
#pragma unroll
  for (int m = 1; m < 64; m <<= 1) v += __shfl_xor(v, m, 64);
  return v;
}

// ---------------- prep: split W into fragment-major packed bf16 hi/lo ----------------
// dst[((c*NF + nf)*64 + lane)*8 + j] = W[o][k], o = nf*16 + (lane&15),
// k = c*32 + (lane>>4)*8 + j.  A wave's B-fragment load is 64 lanes x 16B contiguous.
__global__ void pack_kernel(const float* __restrict__ src, short* __restrict__ hi,
                            short* __restrict__ lo, int Oreal, int NF, int Kreal, int nchunk) {
  int idx = blockIdx.x * 256 + threadIdx.x;
  int total = nchunk * NF * 512;
  if (idx >= total) return;
  int j    = idx & 7;
  int lane = (idx >> 3) & 63;
  int nf   = (idx >> 9) % NF;
  int c    = idx / (NF * 512);
  int o = nf * 16 + (lane & 15);
  int k = c * 32 + ((lane >> 4) << 3) + j;
  float v = (o < Oreal && k < Kreal) ? src[(size_t)o * Kreal + k] : 0.f;
  short h = f2bf(v);
  hi[idx] = h;
  lo[idx] = f2bf(v - bf2f(h));
}

// ---------------- Kernel 1: GCN via split-bf16 MFMA, no K-loop barriers ----------------
// 384 threads (6 waves). Wave: 16 rows x 64 cols. Block: 96 rows = 16 batches. grid 1024.
__global__ __launch_bounds__(384) void gcn_mfma(
    const float* __restrict__ seq1, const float* __restrict__ seq2,
    const float* __restrict__ adj1, const float* __restrict__ adj2,
    const short* __restrict__ Gh, const short* __restrict__ Gl,
    const float* __restrict__ bias, const float* __restrict__ aP,
    float* __restrict__ h1, float* __restrict__ h2)
{
  __shared__ float fts[96][68];
  const int tid = threadIdx.x;
  const int sid = blockIdx.x >> 9;
  const int bb  = blockIdx.x & 511;
  const float* __restrict__ seq = sid ? seq2 : seq1;
  const float* __restrict__ adj = sid ? adj2 : adj1;
  float* __restrict__ hout = sid ? h2 : h1;
  const int b0 = bb << 4;
  const int row0 = b0 * SUBG;
  const int w = tid >> 6, lane = tid & 63;
  const int l15 = lane & 15, lg = lane >> 4;

  f32x4 acc[4];
#pragma unroll
  for (int i = 0; i < 4; ++i) acc[i] = (f32x4){0.f, 0.f, 0.f, 0.f};

  const float* aptr = seq + (size_t)(row0 + w * 16 + l15) * NIN;
  const short* gh = Gh + lane * 8;
  const short* gl = Gl + lane * 8;

  float av[8], nv[8];

#define LOADA(c_, v_)                                                        \
  {                                                                          \
    const int k0 = (c_) * 32 + lg * 8;                                       \
    if (k0 + 8 <= NIN) {                                                     \
      float4 p_, q_;                                                         \
      __builtin_memcpy(&p_, aptr + k0, 16);                                  \
      __builtin_memcpy(&q_, aptr + k0 + 4, 16);                              \
      v_[0] = p_.x; v_[1] = p_.y; v_[2] = p_.z; v_[3] = p_.w;                \
      v_[4] = q_.x; v_[5] = q_.y; v_[6] = q_.z; v_[7] = q_.w;                \
    } else {                                                                 \
      _Pragma("unroll")                                                      \
      for (int j_ = 0; j_ < 8; ++j_) {                                       \
        int k_ = k0 + j_;                                                    \
        v_[j_] = (k_ < NIN) ? aptr[k_] : 0.f;                                \
      }                                                                      \
    }                                                                        \
  }

  LOADA(0, av);
  for (int c = 0; c < KC_G; ++c) {
    if (c + 1 < KC_G) LOADA(c + 1, nv);
    bf16x8 Ah, Al;
#pragma unroll
    for (int j = 0; j < 8; ++j) {
      short h = f2bf(av[j]);
      Ah[j] = h;
      Al[j] = f2bf(av[j] - bf2f(h));
    }
#pragma unroll
    for (int nf = 0; nf < 4; ++nf) {
      const size_t boff = ((size_t)(c * 4 + nf)) << 9;  // *512 elements
      bf16x8 Bh = *(const bf16x8*)(gh + boff);
      bf16x8 Bl = *(const bf16x8*)(gl + boff);
      acc[nf] = __builtin_amdgcn_mfma_f32_16x16x32_bf16(Ah, Bh, acc[nf], 0, 0, 0);
      acc[nf] = __builtin_amdgcn_mfma_f32_16x16x32_bf16(Al, Bh, acc[nf], 0, 0, 0);
      acc[nf] = __builtin_amdgcn_mfma_f32_16x16x32_bf16(Ah, Bl, acc[nf], 0, 0, 0);
    }
#pragma unroll
    for (int j = 0; j < 8; ++j) av[j] = nv[j];
  }
#undef LOADA

  // C frags -> fts LDS (D: row=(l>>4)*4+j, col=l&15)
#pragma unroll
  for (int nf = 0; nf < 4; ++nf)
#pragma unroll
    for (int j = 0; j < 4; ++j)
      fts[w * 16 + lg * 4 + j][nf * 16 + l15] = acc[nf][j];
  __syncthreads();

  // adjacency combine + bias + prelu. thread: col = tid&63, n = tid>>6 (0..5)
  const float a = aP[0];
  const int ccol = tid & 63, nn = tid >> 6;
  const float bv = bias[ccol];
  for (int b = 0; b < 16; ++b) {
    const float* Ab = adj + (size_t)(b0 + b) * 36 + nn * 6;
    float o = bv;
#pragma unroll
    for (int m = 0; m < 6; ++m) o = fmaf(Ab[m], fts[b * 6 + m][ccol], o);
    o = (o >= 0.f) ? o : a * o;
    hout[((size_t)(b0 + b) * SUBG + nn) * NH + ccol] = o;
  }
}

// ---------------- Kernel 2: sinkhorn score + t = discW @ c ----------------
__global__ __launch_bounds__(256) void sink_kernel(
    const float* __restrict__ h1, const float* __restrict__ h2,
    const float* __restrict__ resc, const float* __restrict__ discW,
    float* __restrict__ out, float* __restrict__ tws)
{
  const int b = (blockIdx.x << 2) + (threadIdx.x >> 6);
  const int lane = threadIdx.x & 63;
  const float* p1 = h1 + (size_t)b * (SUBG * NH);
  const float* p2 = h2 + (size_t)b * (SUBG * NH);
  float g1[5], g2[5];
#pragma unroll
  for (int i = 0; i < 4; ++i) { g1[i] = p1[i * 64 + lane]; g2[i] = p2[i * 64 + lane]; }
  g1[4] = p1[5 * 64 + lane];  g2[4] = p2[5 * 64 + lane];
  const float n1 = p1[4 * 64 + lane], n2 = p2[4 * 64 + lane];

  {
    float cm = (g1[0] + g1[1] + g1[2] + g1[3] + n1) * 0.2f;
    float t = 0.f;
    const float4* W4 = (const float4*)discW;
#pragma unroll 4
    for (int jq = 0; jq < 16; ++jq) {
      float4 w = W4[lane * 16 + jq];
      t = fmaf(w.x, __shfl(cm, 4 * jq, 64), t);
      t = fmaf(w.y, __shfl(cm, 4 * jq + 1, 64), t);
      t = fmaf(w.z, __shfl(cm, 4 * jq + 2, 64), t);
      t = fmaf(w.w, __shfl(cm, 4 * jq + 3, 64), t);
    }
    tws[(size_t)b * 64 + lane] = t;
  }

  float in1[5], in2[5];
#pragma unroll
  for (int i = 0; i < 5; ++i) {
    float s = allred64(g1[i] * g1[i]);
    in1[i] = 1.f / fmaxf(sqrtf(s), 1e-12f);
    s = allred64(g2[i] * g2[i]);
    in2[i] = 1.f / fmaxf(sqrtf(s), 1e-12f);
  }
  float cost[25], P[25];
#pragma unroll
  for (int i = 0; i < 5; ++i)
#pragma unroll
    for (int j = 0; j < 5; ++j) {
      float d = allred64(g1[i] * g2[j]);
      float cv = (1.f - d * in1[i] * in2[j]) * resc[(size_t)b * 25 + i * 5 + j];
      cost[i * 5 + j] = cv;
      P[i * 5 + j] = expf(-20.f * cv);
    }
  float r[5], c[5];
  float rs = 0.f, cs = 0.f;
#pragma unroll
  for (int i = 0; i < 5; ++i) {
    float d = allred64(g1[i] * n2); d = (d <= 0.f) ? 1e-8f : d; r[i] = d; rs += d;
    d = allred64(g2[i] * n1);       d = (d <= 0.f) ? 1e-8f : d; c[i] = d; cs += d;
  }
#pragma unroll
  for (int i = 0; i < 5; ++i) { r[i] = r[i] / rs; c[i] = c[i] / cs; }

  float u[5], v[5];
#pragma unroll
  for (int i = 0; i < 5; ++i) u[i] = 0.2f;
#pragma unroll
  for (int it = 0; it < 5; ++it) {
#pragma unroll
    for (int i = 0; i < 5; ++i) {
      float pv = 0.f;
#pragma unroll
      for (int j = 0; j < 5; ++j) pv = fmaf(P[i * 5 + j], u[j], pv);
      v[i] = r[i] / pv;
    }
#pragma unroll
    for (int i = 0; i < 5; ++i) {
      float pu = 0.f;
#pragma unroll
      for (int j = 0; j < 5; ++j) pu = fmaf(P[j * 5 + i], v[j], pu);
      u[i] = c[i] / pu;
    }
  }
  float S = 0.f;
#pragma unroll
  for (int i = 0; i < 5; ++i)
#pragma unroll
    for (int j = 0; j < 5; ++j)
      S += v[i] * P[i * 5 + j] * u[j] * (1.f - cost[i * 5 + j]);
  if (lane == 0) out[(size_t)b * 1436] = expf(S * 2.5f) * 2.f;
}

// ---------------- Kernel 3a: decoder layers 1+2 (MFMA) -> x3 ----------------
// 1 wave per block, 16 rows; grid 512
__global__ __launch_bounds__(64) void dec12_mfma(
    const float* __restrict__ h1,
    const short* __restrict__ B1h, const short* __restrict__ B1l,
    const float* __restrict__ b1, const float* __restrict__ a1P,
    const short* __restrict__ B2h, const short* __restrict__ B2l,
    const float* __restrict__ b2, const float* __restrict__ a2P,
    float* __restrict__ x3)
{
  __shared__ float xT[16][132];
  const int lane = threadIdx.x;
  const int l15 = lane & 15, lg = lane >> 4;
  const int r0 = blockIdx.x * 16;

  f32x4 acc[8];
#pragma unroll
  for (int i = 0; i < 8; ++i) acc[i] = (f32x4){0.f, 0.f, 0.f, 0.f};

  // ---- layer 1: K=256, O=128 ----
#pragma unroll
  for (int c = 0; c < 8; ++c) {
    const float* ap = h1 + (size_t)(r0 + l15) * 384 + c * 32 + lg * 8;
    float4 p = *(const float4*)ap;
    float4 q = *(const float4*)(ap + 4);
    float av[8] = {p.x, p.y, p.z, p.w, q.x, q.y, q.z, q.w};
    bf16x8 Ah, Al;
#pragma unroll
    for (int j = 0; j < 8; ++j) { short h = f2bf(av[j]); Ah[j] = h; Al[j] = f2bf(av[j] - bf2f(h)); }
#pragma unroll
    for (int nf = 0; nf < 8; ++nf) {
      size_t off = (((size_t)(c * 8 + nf)) << 9) + (size_t)lane * 8;
      bf16x8 Bh = *(const bf16x8*)(B1h + off);
      bf16x8 Bl = *(const bf16x8*)(B1l + off);
      acc[nf] = __builtin_amdgcn_mfma_f32_16x16x32_bf16(Ah, Bh, acc[nf], 0, 0, 0);
      acc[nf] = __builtin_amdgcn_mfma_f32_16x16x32_bf16(Al, Bh, acc[nf], 0, 0, 0);
      acc[nf] = __builtin_amdgcn_mfma_f32_16x16x32_bf16(Ah, Bl, acc[nf], 0, 0, 0);
    }
  }
  {
    const float a1 = a1P[0];
#pragma unroll
    for (int nf = 0; nf < 8; ++nf) {
      int o = nf * 16 + l15;
      float bv = b1[o];
#pragma unroll
      for (int j = 0; j < 4; ++j) {
        float v = acc[nf][j] + bv;
        xT[lg * 4 + j][o] = (v >= 0.f) ? v : a1 * v;
      }
    }
  }
  __syncthreads();

  // ---- layer 2: K=128, O=128 ----
#pragma unroll
  for (int i = 0; i < 8; ++i) acc[i] = (f32x4){0.f, 0.f, 0.f, 0.f};
#pragma unroll
  for (int c = 0; c < 4; ++c) {
    const float* ap = &xT[l15][c * 32 + lg * 8];
    float4 p = *(const float4*)ap;
    float4 q = *(const float4*)(ap + 4);
    float av[8] = {p.x, p.y, p.z, p.w, q.x, q.y, q.z, q.w};
    bf16x8 Ah, Al;
#pragma unroll
    for (int j = 0; j < 8; ++j) { short h = f2bf(av[j]); Ah[j] = h; Al[j] = f2bf(av[j] - bf2f(h)); }
#pragma unroll
    for (int nf = 0; nf < 8; ++nf) {
      size_t off = (((size_t)(c * 8 + nf)) << 9) + (size_t)lane * 8;
      bf16x8 Bh = *(const bf16x8*)(B2h + off);
      bf16x8 Bl = *(const bf16x8*)(B2l + off);
      acc[nf] = __builtin_amdgcn_mfma_f32_16x16x32_bf16(Ah, Bh, acc[nf], 0, 0, 0);
      acc[nf] = __builtin_amdgcn_mfma_f32_16x16x32_bf16(Al, Bh, acc[nf], 0, 0, 0);
      acc[nf] = __builtin_amdgcn_mfma_f32_16x16x32_bf16(Ah, Bl, acc[nf], 0, 0, 0);
    }
  }
  {
    const float a2 = a2P[0];
#pragma unroll
    for (int nf = 0; nf < 8; ++nf) {
      int o = nf * 16 + l15;
      float bv = b2[o];
#pragma unroll
      for (int j = 0; j < 4; ++j) {
        float v = acc[nf][j] + bv;
        v = (v >= 0.f) ? v : a2 * v;
        x3[(size_t)(r0 + lg * 4 + j) * 128 + o] = v;
      }
    }
  }
}

// ---------------- Kernel 3b: decoder layer 3 (MFMA, nf-split) ----------------
// 1 wave per block; grid = 512 rowblocks x 6 nf-groups
__global__ __launch_bounds__(64) void dec3_mfma(
    const float* __restrict__ x3,
    const short* __restrict__ B3h, const short* __restrict__ B3l,
    const float* __restrict__ b3, const float* __restrict__ a3P,
    float* __restrict__ out)
{
  const int lane = threadIdx.x;
  const int l15 = lane & 15, lg = lane >> 4;
  const int rowblk = blockIdx.x & 511;
  const int nfg = blockIdx.x >> 9;     // 0..5, 15 nf each (90 total)
  const int r0 = rowblk * 16;

  bf16x8 A3h[4], A3l[4];
#pragma unroll
  for (int c = 0; c < 4; ++c) {
    const float* ap = x3 + (size_t)(r0 + l15) * 128 + c * 32 + lg * 8;
    float4 p = *(const float4*)ap;
    float4 q = *(const float4*)(ap + 4);
    float av[8] = {p.x, p.y, p.z, p.w, q.x, q.y, q.z, q.w};
#pragma unroll
    for (int j = 0; j < 8; ++j) {
      short h = f2bf(av[j]); A3h[c][j] = h; A3l[c][j] = f2bf(av[j] - bf2f(h));
    }
  }
  const float a3 = a3P[0];
  for (int t = 0; t < 15; ++t) {
    const int nf = nfg * 15 + t;
    f32x4 acc = (f32x4){0.f, 0.f, 0.f, 0.f};
#pragma unroll
    for (int c = 0; c < 4; ++c) {
      size_t off = (((size_t)(c * 90 + nf)) << 9) + (size_t)lane * 8;
      bf16x8 Bh = *(const bf16x8*)(B3h + off);
      bf16x8 Bl = *(const bf16x8*)(B3l + off);
      acc = __builtin_amdgcn_mfma_f32_16x16x32_bf16(A3h[c], Bh, acc, 0, 0, 0);
      acc = __builtin_amdgcn_mfma_f32_16x16x32_bf16(A3l[c], Bh, acc, 0, 0, 0);
      acc = __builtin_amdgcn_mfma_f32_16x16x32_bf16(A3h[c], Bl, acc, 0, 0, 0);
    }
    const int o = nf * 16 + l15;
    if (o < NIN) {
      float bv = b3[o];
#pragma unroll
      for (int j = 0; j < 4; ++j) {
        float v = acc[j] + bv;
        v = (v >= 0.f) ? v : a3 * v;
        out[(size_t)(r0 + lg * 4 + j) * 1436 + 1 + o] = v;
      }
    }
  }
}

// ---------------- Kernel 4: discriminator logits ----------------
__global__ __launch_bounds__(256) void disc_kernel(
    const float* __restrict__ h1, const float* __restrict__ tws,
    const float* __restrict__ dbP, float* __restrict__ out)
{
  const int b = (blockIdx.x << 2) + (threadIdx.x >> 6);
  const int lane = threadIdx.x & 63;
  float hp = h1[((size_t)b * SUBG + 5) * NH + lane];
  float t0 = tws[(size_t)b * 64 + lane];
  int bp = (b == 0) ? (BB - 2) : (b - 1);
  float tp = tws[(size_t)bp * 64 + lane];
  float s1 = allred64(hp * t0);
  float s2 = allred64(hp * tp);
  if (lane == 0) {
    float db = dbP[0];
    out[(size_t)b * 1436 + 1434] = s1 + db;
    out[(size_t)b * 1436 + 1435] = s2 + db;
  }
}

extern "C" void kernel_launch(void* const* d_in, const int* in_sizes, int n_in,
                              void* d_out, int out_size, void* d_ws, size_t ws_size,
                              hipStream_t stream) {
  (void)in_sizes; (void)n_in; (void)out_size; (void)ws_size;
  const float* seq1  = (const float*)d_in[0];
  const float* seq2  = (const float*)d_in[1];
  const float* adj1  = (const float*)d_in[2];
  const float* adj2  = (const float*)d_in[3];
  const float* resc  = (const float*)d_in[4];
  const float* gcnW  = (const float*)d_in[5];
  const float* gcnB  = (const float*)d_in[6];
  const float* gcnA  = (const float*)d_in[7];
  const float* W1    = (const float*)d_in[8];
  const float* b1    = (const float*)d_in[9];
  const float* a1    = (const float*)d_in[10];
  const float* W2    = (const float*)d_in[11];
  const float* b2    = (const float*)d_in[12];
  const float* a2    = (const float*)d_in[13];
  const float* W3    = (const float*)d_in[14];
  const float* b3    = (const float*)d_in[15];
  const float* a3    = (const float*)d_in[16];
  const float* discW = (const float*)d_in[17];
  const float* discB = (const float*)d_in[18];

  float* h1  = (float*)d_ws;                   // 8192*384
  float* h2  = h1 + (size_t)BB * SUBG * NH;    // 8192*384
  float* tws = h2 + (size_t)BB * SUBG * NH;    // 8192*64
  float* x3  = tws + (size_t)BB * 64;          // 8192*128
  short* Gh  = (short*)(x3 + (size_t)BB * 128);
  short* Gl  = Gh  + 45 * 4 * 512;
  short* B1h = Gl  + 45 * 4 * 512;
  short* B1l = B1h + 8 * 8 * 512;
  short* B2h = B1l + 8 * 8 * 512;
  short* B2l = B2h + 4 * 8 * 512;
  short* B3h = B2l + 4 * 8 * 512;
  short* B3l = B3h + 4 * 90 * 512;
  float* out = (float*)d_out;

  pack_kernel<<<(45 * 4 * 512 + 255) / 256, 256, 0, stream>>>(gcnW, Gh, Gl, 64, 4, 1433, 45);
  pack_kernel<<<(8 * 8 * 512 + 255) / 256, 256, 0, stream>>>(W1, B1h, B1l, 128, 8, 256, 8);
  pack_kernel<<<(4 * 8 * 512 + 255) / 256, 256, 0, stream>>>(W2, B2h, B2l, 128, 8, 128, 4);
  pack_kernel<<<(4 * 90 * 512 + 255) / 256, 256, 0, stream>>>(W3, B3h, B3l, 1433, 90, 128, 4);

  gcn_mfma<<<1024, 384, 0, stream>>>(seq1, seq2, adj1, adj2, Gh, Gl, gcnB, gcnA, h1, h2);
  sink_kernel<<<2048, 256, 0, stream>>>(h1, h2, resc, discW, out, tws);
  dec12_mfma<<<512, 64, 0, stream>>>(h1, B1h, B1l, b1, a1, B2h, B2l, b2, a2, x3);
  dec3_mfma<<<3072, 64, 0, stream>>>(x3, B3h, B3l, b3, a3, out);
  disc_kernel<<<2048, 256, 0, stream>>>(h1, tws, discB, out);
}

// Round 4
// 418.927 us; speedup vs baseline: 1.1332x; 1.1332x over previous
//
#include <hip/hip_runtime.h>
#include <math.h>

#define BB   8192
#define NIN  1433
#define NH   64
#define SUBG 6
#define HID  128

typedef __attribute__((ext_vector_type(8))) short bf16x8;
typedef __attribute__((ext_vector_type(4))) float f32x4;

__device__ __forceinline__ short f2bf(float x) {
  unsigned u = __float_as_uint(x);
  unsigned r = (u + 0x7fffu + ((u >> 16) & 1u)) >> 16;   // RNE
  return (short)r;
}
__device__ __forceinline__ float bf2f(short s) {
  return __uint_as_float(((unsigned)(unsigned short)s) << 16);
}
__device__ __forceinline__ float allred64(float v) {
#pragma unroll
  for (int m = 1; m < 64; m <<= 1) v += __shfl_xor(v, m, 64);
  return v;
}

__device__ __forceinline__ void gload_lds16(const short* g, short* l) {
  __builtin_amdgcn_global_load_lds(
      (const __attribute__((address_space(1))) void*)g,
      (__attribute__((address_space(3))) void*)l, 16, 0, 0);
}

#define WAITV(N)                                            \
  {                                                         \
    asm volatile("s_waitcnt vmcnt(" #N ")" ::: "memory");   \
    __builtin_amdgcn_sched_barrier(0);                      \
  }
#define BARRIER()                                           \
  {                                                         \
    __builtin_amdgcn_s_barrier();                           \
    __builtin_amdgcn_sched_barrier(0);                      \
  }

// ---------------- prep: split W into fragment-major packed bf16 hi/lo ----------------
// dst[((c*NF + nf)*64 + lane)*8 + j] = W[o][k], o = nf*16 + (lane&15),
// k = c*32 + (lane>>4)*8 + j.
__global__ void pack_kernel(const float* __restrict__ src, short* __restrict__ hi,
                            short* __restrict__ lo, int Oreal, int NF, int Kreal, int nchunk) {
  int idx = blockIdx.x * 256 + threadIdx.x;
  int total = nchunk * NF * 512;
  if (idx >= total) return;
  int j    = idx & 7;
  int lane = (idx >> 3) & 63;
  int nf   = (idx >> 9) % NF;
  int c    = idx / (NF * 512);
  int o = nf * 16 + (lane & 15);
  int k = c * 32 + ((lane >> 4) << 3) + j;
  float v = (o < Oreal && k < Kreal) ? src[(size_t)o * Kreal + k] : 0.f;
  short h = f2bf(v);
  hi[idx] = h;
  lo[idx] = f2bf(v - bf2f(h));
}

// ---------------- Kernel 1: GCN, pipelined split-bf16 MFMA ----------------
// 384 threads (6 waves). Wave: 16 rows x 64 cols. Block: 96 rows = 16 batches. grid 1024.
// B: LDS ring of 4 slots, global_load_lds, issue-ahead-2, counted vmcnt(4).
// A: per-lane regs, asm global_load_dwordx4, prefetch depth 2 (named sets).
__global__ __launch_bounds__(384, 3) void gcn_mfma(
    const float* __restrict__ seq1, const float* __restrict__ seq2,
    const float* __restrict__ adj1, const float* __restrict__ adj2,
    const short* __restrict__ Gh, const short* __restrict__ Gl,
    const float* __restrict__ bias, const float* __restrict__ aP,
    float* __restrict__ h1, float* __restrict__ h2)
{
  __shared__ short sB[4][6144];       // 4 slots x 12KB: [hi 4KB][lo 4KB][pad 4KB]
  __shared__ float fts[96][68];
  const int tid = threadIdx.x;
  const int sid = blockIdx.x >> 9;
  const int bb  = blockIdx.x & 511;
  const float* __restrict__ seq = sid ? seq2 : seq1;
  const float* __restrict__ adj = sid ? adj2 : adj1;
  float* __restrict__ hout = sid ? h2 : h1;
  const int b0 = bb << 4;
  const int row0 = b0 * SUBG;
  const int w = tid >> 6, lane = tid & 63;
  const int l15 = lane & 15, lg = lane >> 4;

  f32x4 acc[4];
#pragma unroll
  for (int i = 0; i < 4; ++i) acc[i] = (f32x4){0.f, 0.f, 0.f, 0.f};

  const float* aptr = seq + (size_t)(row0 + w * 16 + l15) * NIN;

  // stage B chunk c into slot c&3 : exactly 2 global_load_lds per thread
  auto STAGE = [&](int c) {
    short* slotp = &sB[c & 3][0];
#pragma unroll
    for (int i = 0; i < 2; ++i) {
      const int pbase = w * 128 + i * 64;            // wave-uniform, in {0..704}
      const short* gb;
      if (pbase < 256)      gb = Gh + ((size_t)c * 256 + pbase) * 8;
      else if (pbase < 512) gb = Gl + ((size_t)c * 256 + (pbase - 256)) * 8;
      else                  gb = Gh + ((size_t)c * 256 + (pbase - 512)) * 8;  // pad dup
      gload_lds16(gb + (size_t)lane * 8, slotp + pbase * 8);
    }
  };
  // A chunk c (k = c*32 + lg*8 .. +8) : exactly 2 asm dwordx4 per thread
  auto ALOAD = [&](int c, f32x4& p, f32x4& q) {
    const float* ad = aptr + c * 32 + lg * 8;
    asm volatile("global_load_dwordx4 %0, %2, off\n\t"
                 "global_load_dwordx4 %1, %2, off offset:16"
                 : "=v"(p), "=v"(q) : "v"(ad));
  };
  auto COMPUTE = [&](int c, const f32x4& p, const f32x4& q) {
    float av[8] = {p[0], p[1], p[2], p[3], q[0], q[1], q[2], q[3]};
    bf16x8 Ah, Al;
#pragma unroll
    for (int j = 0; j < 8; ++j) {
      short h = f2bf(av[j]);
      Ah[j] = h;
      Al[j] = f2bf(av[j] - bf2f(h));
    }
    const short* bs = &sB[c & 3][0];
#pragma unroll
    for (int nf = 0; nf < 4; ++nf) {
      bf16x8 Bh = *(const bf16x8*)(bs + (nf * 64 + lane) * 8);
      bf16x8 Bl = *(const bf16x8*)(bs + 2048 + (nf * 64 + lane) * 8);
      acc[nf] = __builtin_amdgcn_mfma_f32_16x16x32_bf16(Ah, Bh, acc[nf], 0, 0, 0);
      acc[nf] = __builtin_amdgcn_mfma_f32_16x16x32_bf16(Al, Bh, acc[nf], 0, 0, 0);
      acc[nf] = __builtin_amdgcn_mfma_f32_16x16x32_bf16(Ah, Bl, acc[nf], 0, 0, 0);
    }
  };

  f32x4 p0, q0, p1, q1, p2, q2;
  // prologue: issue A then B per chunk (stream: A0,B0,A1,B1)
  ALOAD(0, p0, q0); STAGE(0);
  ALOAD(1, p1, q1); STAGE(1);

  // steady bodies 0..41 (14 triples); each: wait(4), barrier, issue c+2, compute c
  for (int cc = 0; cc < 42; cc += 3) {
    WAITV(4); BARRIER();
    ALOAD(cc + 2, p2, q2); STAGE(cc + 2);
    COMPUTE(cc, p0, q0);
    WAITV(4); BARRIER();
    ALOAD(cc + 3, p0, q0); STAGE(cc + 3);
    COMPUTE(cc + 1, p1, q1);
    WAITV(4); BARRIER();
    ALOAD(cc + 4, p1, q1); STAGE(cc + 4);
    COMPUTE(cc + 2, p2, q2);
  }
  // bodies 42, 43 (no further issues)
  WAITV(4); BARRIER();
  COMPUTE(42, p0, q0);
  WAITV(0); BARRIER();
  COMPUTE(43, p1, q1);

  // epilogue chunk 44: k = 1408..1439 (valid < 1433), B straight from global (L2)
  {
    const int k0 = 44 * 32 + lg * 8;
    float av[8];
#pragma unroll
    for (int j = 0; j < 8; ++j) {
      int k = k0 + j;
      av[j] = (k < NIN) ? aptr[k] : 0.f;
    }
    bf16x8 Ah, Al;
#pragma unroll
    for (int j = 0; j < 8; ++j) {
      short h = f2bf(av[j]);
      Ah[j] = h;
      Al[j] = f2bf(av[j] - bf2f(h));
    }
#pragma unroll
    for (int nf = 0; nf < 4; ++nf) {
      const size_t off = ((size_t)(44 * 4 + nf) * 64 + lane) * 8;
      bf16x8 Bh = *(const bf16x8*)(Gh + off);
      bf16x8 Bl = *(const bf16x8*)(Gl + off);
      acc[nf] = __builtin_amdgcn_mfma_f32_16x16x32_bf16(Ah, Bh, acc[nf], 0, 0, 0);
      acc[nf] = __builtin_amdgcn_mfma_f32_16x16x32_bf16(Al, Bh, acc[nf], 0, 0, 0);
      acc[nf] = __builtin_amdgcn_mfma_f32_16x16x32_bf16(Ah, Bl, acc[nf], 0, 0, 0);
    }
  }

  // C frags -> fts LDS (D: row=(l>>4)*4+j, col=l&15)
#pragma unroll
  for (int nf = 0; nf < 4; ++nf)
#pragma unroll
    for (int j = 0; j < 4; ++j)
      fts[w * 16 + lg * 4 + j][nf * 16 + l15] = acc[nf][j];
  __syncthreads();

  // adjacency combine + bias + prelu. thread: col = tid&63, n = tid>>6 (0..5)
  const float a = aP[0];
  const int ccol = tid & 63, nn = tid >> 6;
  const float bv = bias[ccol];
  for (int b = 0; b < 16; ++b) {
    const float* Ab = adj + (size_t)(b0 + b) * 36 + nn * 6;
    float o = bv;
#pragma unroll
    for (int m = 0; m < 6; ++m) o = fmaf(Ab[m], fts[b * 6 + m][ccol], o);
    o = (o >= 0.f) ? o : a * o;
    hout[((size_t)(b0 + b) * SUBG + nn) * NH + ccol] = o;
  }
}

// ---------------- Kernel 2: sinkhorn score + t = discW @ c ----------------
__global__ __launch_bounds__(256) void sink_kernel(
    const float* __restrict__ h1, const float* __restrict__ h2,
    const float* __restrict__ resc, const float* __restrict__ discW,
    float* __restrict__ out, float* __restrict__ tws)
{
  const int b = (blockIdx.x << 2) + (threadIdx.x >> 6);
  const int lane = threadIdx.x & 63;
  const float* p1 = h1 + (size_t)b * (SUBG * NH);
  const float* p2 = h2 + (size_t)b * (SUBG * NH);
  float g1[5], g2[5];
#pragma unroll
  for (int i = 0; i < 4; ++i) { g1[i] = p1[i * 64 + lane]; g2[i] = p2[i * 64 + lane]; }
  g1[4] = p1[5 * 64 + lane];  g2[4] = p2[5 * 64 + lane];
  const float n1 = p1[4 * 64 + lane], n2 = p2[4 * 64 + lane];

  {
    float cm = (g1[0] + g1[1] + g1[2] + g1[3] + n1) * 0.2f;
    float t = 0.f;
    const float4* W4 = (const float4*)discW;
#pragma unroll 4
    for (int jq = 0; jq < 16; ++jq) {
      float4 w = W4[lane * 16 + jq];
      t = fmaf(w.x, __shfl(cm, 4 * jq, 64), t);
      t = fmaf(w.y, __shfl(cm, 4 * jq + 1, 64), t);
      t = fmaf(w.z, __shfl(cm, 4 * jq + 2, 64), t);
      t = fmaf(w.w, __shfl(cm, 4 * jq + 3, 64), t);
    }
    tws[(size_t)b * 64 + lane] = t;
  }

  float in1[5], in2[5];
#pragma unroll
  for (int i = 0; i < 5; ++i) {
    float s = allred64(g1[i] * g1[i]);
    in1[i] = 1.f / fmaxf(sqrtf(s), 1e-12f);
    s = allred64(g2[i] * g2[i]);
    in2[i] = 1.f / fmaxf(sqrtf(s), 1e-12f);
  }
  float cost[25], P[25];
#pragma unroll
  for (int i = 0; i < 5; ++i)
#pragma unroll
    for (int j = 0; j < 5; ++j) {
      float d = allred64(g1[i] * g2[j]);
      float cv = (1.f - d * in1[i] * in2[j]) * resc[(size_t)b * 25 + i * 5 + j];
      cost[i * 5 + j] = cv;
      P[i * 5 + j] = expf(-20.f * cv);
    }
  float r[5], c[5];
  float rs = 0.f, cs = 0.f;
#pragma unroll
  for (int i = 0; i < 5; ++i) {
    float d = allred64(g1[i] * n2); d = (d <= 0.f) ? 1e-8f : d; r[i] = d; rs += d;
    d = allred64(g2[i] * n1);       d = (d <= 0.f) ? 1e-8f : d; c[i] = d; cs += d;
  }
#pragma unroll
  for (int i = 0; i < 5; ++i) { r[i] = r[i] / rs; c[i] = c[i] / cs; }

  float u[5], v[5];
#pragma unroll
  for (int i = 0; i < 5; ++i) u[i] = 0.2f;
#pragma unroll
  for (int it = 0; it < 5; ++it) {
#pragma unroll
    for (int i = 0; i < 5; ++i) {
      float pv = 0.f;
#pragma unroll
      for (int j = 0; j < 5; ++j) pv = fmaf(P[i * 5 + j], u[j], pv);
      v[i] = r[i] / pv;
    }
#pragma unroll
    for (int i = 0; i < 5; ++i) {
      float pu = 0.f;
#pragma unroll
      for (int j = 0; j < 5; ++j) pu = fmaf(P[j * 5 + i], v[j], pu);
      u[i] = c[i] / pu;
    }
  }
  float S = 0.f;
#pragma unroll
  for (int i = 0; i < 5; ++i)
#pragma unroll
    for (int j = 0; j < 5; ++j)
      S += v[i] * P[i * 5 + j] * u[j] * (1.f - cost[i * 5 + j]);
  if (lane == 0) out[(size_t)b * 1436] = expf(S * 2.5f) * 2.f;
}

// ---------------- Kernel 3a: decoder layers 1+2 (MFMA) -> x3 ----------------
__global__ __launch_bounds__(64) void dec12_mfma(
    const float* __restrict__ h1,
    const short* __restrict__ B1h, const short* __restrict__ B1l,
    const float* __restrict__ b1, const float* __restrict__ a1P,
    const short* __restrict__ B2h, const short* __restrict__ B2l,
    const float* __restrict__ b2, const float* __restrict__ a2P,
    float* __restrict__ x3)
{
  __shared__ float xT[16][132];
  const int lane = threadIdx.x;
  const int l15 = lane & 15, lg = lane >> 4;
  const int r0 = blockIdx.x * 16;

  f32x4 acc[8];
#pragma unroll
  for (int i = 0; i < 8; ++i) acc[i] = (f32x4){0.f, 0.f, 0.f, 0.f};

  // ---- layer 1: K=256, O=128 ----
#pragma unroll
  for (int c = 0; c < 8; ++c) {
    const float* ap = h1 + (size_t)(r0 + l15) * 384 + c * 32 + lg * 8;
    float4 p = *(const float4*)ap;
    float4 q = *(const float4*)(ap + 4);
    float av[8] = {p.x, p.y, p.z, p.w, q.x, q.y, q.z, q.w};
    bf16x8 Ah, Al;
#pragma unroll
    for (int j = 0; j < 8; ++j) { short h = f2bf(av[j]); Ah[j] = h; Al[j] = f2bf(av[j] - bf2f(h)); }
#pragma unroll
    for (int nf = 0; nf < 8; ++nf) {
      size_t off = (((size_t)(c * 8 + nf)) << 9) + (size_t)lane * 8;
      bf16x8 Bh = *(const bf16x8*)(B1h + off);
      bf16x8 Bl = *(const bf16x8*)(B1l + off);
      acc[nf] = __builtin_amdgcn_mfma_f32_16x16x32_bf16(Ah, Bh, acc[nf], 0, 0, 0);
      acc[nf] = __builtin_amdgcn_mfma_f32_16x16x32_bf16(Al, Bh, acc[nf], 0, 0, 0);
      acc[nf] = __builtin_amdgcn_mfma_f32_16x16x32_bf16(Ah, Bl, acc[nf], 0, 0, 0);
    }
  }
  {
    const float a1 = a1P[0];
#pragma unroll
    for (int nf = 0; nf < 8; ++nf) {
      int o = nf * 16 + l15;
      float bv = b1[o];
#pragma unroll
      for (int j = 0; j < 4; ++j) {
        float v = acc[nf][j] + bv;
        xT[lg * 4 + j][o] = (v >= 0.f) ? v : a1 * v;
      }
    }
  }
  __syncthreads();

  // ---- layer 2: K=128, O=128 ----
#pragma unroll
  for (int i = 0; i < 8; ++i) acc[i] = (f32x4){0.f, 0.f, 0.f, 0.f};
#pragma unroll
  for (int c = 0; c < 4; ++c) {
    const float* ap = &xT[l15][c * 32 + lg * 8];
    float4 p = *(const float4*)ap;
    float4 q = *(const float4*)(ap + 4);
    float av[8] = {p.x, p.y, p.z, p.w, q.x, q.y, q.z, q.w};
    bf16x8 Ah, Al;
#pragma unroll
    for (int j = 0; j < 8; ++j) { short h = f2bf(av[j]); Ah[j] = h; Al[j] = f2bf(av[j] - bf2f(h)); }
#pragma unroll
    for (int nf = 0; nf < 8; ++nf) {
      size_t off = (((size_t)(c * 8 + nf)) << 9) + (size_t)lane * 8;
      bf16x8 Bh = *(const bf16x8*)(B2h + off);
      bf16x8 Bl = *(const bf16x8*)(B2l + off);
      acc[nf] = __builtin_amdgcn_mfma_f32_16x16x32_bf16(Ah, Bh, acc[nf], 0, 0, 0);
      acc[nf] = __builtin_amdgcn_mfma_f32_16x16x32_bf16(Al, Bh, acc[nf], 0, 0, 0);
      acc[nf] = __builtin_amdgcn_mfma_f32_16x16x32_bf16(Ah, Bl, acc[nf], 0, 0, 0);
    }
  }
  {
    const float a2 = a2P[0];
#pragma unroll
    for (int nf = 0; nf < 8; ++nf) {
      int o = nf * 16 + l15;
      float bv = b2[o];
#pragma unroll
      for (int j = 0; j < 4; ++j) {
        float v = acc[nf][j] + bv;
        v = (v >= 0.f) ? v : a2 * v;
        x3[(size_t)(r0 + lg * 4 + j) * 128 + o] = v;
      }
    }
  }
}

// ---------------- Kernel 3b: decoder layer 3 (MFMA, nf-split) ----------------
__global__ __launch_bounds__(64) void dec3_mfma(
    const float* __restrict__ x3,
    const short* __restrict__ B3h, const short* __restrict__ B3l,
    const float* __restrict__ b3, const float* __restrict__ a3P,
    float* __restrict__ out)
{
  const int lane = threadIdx.x;
  const int l15 = lane & 15, lg = lane >> 4;
  const int rowblk = blockIdx.x & 511;
  const int nfg = blockIdx.x >> 9;     // 0..5, 15 nf each (90 total)
  const int r0 = rowblk * 16;

  bf16x8 A3h[4], A3l[4];
#pragma unroll
  for (int c = 0; c < 4; ++c) {
    const float* ap = x3 + (size_t)(r0 + l15) * 128 + c * 32 + lg * 8;
    float4 p = *(const float4*)ap;
    float4 q = *(const float4*)(ap + 4);
    float av[8] = {p.x, p.y, p.z, p.w, q.x, q.y, q.z, q.w};
#pragma unroll
    for (int j = 0; j < 8; ++j) {
      short h = f2bf(av[j]); A3h[c][j] = h; A3l[c][j] = f2bf(av[j] - bf2f(h));
    }
  }
  const float a3 = a3P[0];
  for (int t = 0; t < 15; ++t) {
    const int nf = nfg * 15 + t;
    f32x4 acc = (f32x4){0.f, 0.f, 0.f, 0.f};
#pragma unroll
    for (int c = 0; c < 4; ++c) {
      size_t off = (((size_t)(c * 90 + nf)) << 9) + (size_t)lane * 8;
      bf16x8 Bh = *(const bf16x8*)(B3h + off);
      bf16x8 Bl = *(const bf16x8*)(B3l + off);
      acc = __builtin_amdgcn_mfma_f32_16x16x32_bf16(A3h[c], Bh, acc, 0, 0, 0);
      acc = __builtin_amdgcn_mfma_f32_16x16x32_bf16(A3l[c], Bh, acc, 0, 0, 0);
      acc = __builtin_amdgcn_mfma_f32_16x16x32_bf16(A3h[c], Bl, acc, 0, 0, 0);
    }
    const int o = nf * 16 + l15;
    if (o < NIN) {
      float bv = b3[o];
#pragma unroll
      for (int j = 0; j < 4; ++j) {
        float v = acc[j] + bv;
        v = (v >= 0.f) ? v : a3 * v;
        out[(size_t)(r0 + lg * 4 + j) * 1436 + 1 + o] = v;
      }
    }
  }
}

// ---------------- Kernel 4: discriminator logits ----------------
__global__ __launch_bounds__(256) void disc_kernel(
    const float* __restrict__ h1, const float* __restrict__ tws,
    const float* __restrict__ dbP, float* __restrict__ out)
{
  const int b = (blockIdx.x << 2) + (threadIdx.x >> 6);
  const int lane = threadIdx.x & 63;
  float hp = h1[((size_t)b * SUBG + 5) * NH + lane];
  float t0 = tws[(size_t)b * 64 + lane];
  int bp = (b == 0) ? (BB - 2) : (b - 1);
  float tp = tws[(size_t)bp * 64 + lane];
  float s1 = allred64(hp * t0);
  float s2 = allred64(hp * tp);
  if (lane == 0) {
    float db = dbP[0];
    out[(size_t)b * 1436 + 1434] = s1 + db;
    out[(size_t)b * 1436 + 1435] = s2 + db;
  }
}

extern "C" void kernel_launch(void* const* d_in, const int* in_sizes, int n_in,
                              void* d_out, int out_size, void* d_ws, size_t ws_size,
                              hipStream_t stream) {
  (void)in_sizes; (void)n_in; (void)out_size; (void)ws_size;
  const float* seq1  = (const float*)d_in[0];
  const float* seq2  = (const float*)d_in[1];
  const float* adj1  = (const float*)d_in[2];
  const float* adj2  = (const float*)d_in[3];
  const float* resc  = (const float*)d_in[4];
  const float* gcnW  = (const float*)d_in[5];
  const float* gcnB  = (const float*)d_in[6];
  const float* gcnA  = (const float*)d_in[7];
  const float* W1    = (const float*)d_in[8];
  const float* b1    = (const float*)d_in[9];
  const float* a1    = (const float*)d_in[10];
  const float* W2    = (const float*)d_in[11];
  const float* b2    = (const float*)d_in[12];
  const float* a2    = (const float*)d_in[13];
  const float* W3    = (const float*)d_in[14];
  const float* b3    = (const float*)d_in[15];
  const float* a3    = (const float*)d_in[16];
  const float* discW = (const float*)d_in[17];
  const float* discB = (const float*)d_in[18];

  float* h1  = (float*)d_ws;                   // 8192*384
  float* h2  = h1 + (size_t)BB * SUBG * NH;    // 8192*384
  float* tws = h2 + (size_t)BB * SUBG * NH;    // 8192*64
  float* x3  = tws + (size_t)BB * 64;          // 8192*128
  short* Gh  = (short*)(x3 + (size_t)BB * 128);
  short* Gl  = Gh  + 45 * 4 * 512;
  short* B1h = Gl  + 45 * 4 * 512;
  short* B1l = B1h + 8 * 8 * 512;
  short* B2h = B1l + 8 * 8 * 512;
  short* B2l = B2h + 4 * 8 * 512;
  short* B3h = B2l + 4 * 8 * 512;
  short* B3l = B3h + 4 * 90 * 512;
  float* out = (float*)d_out;

  pack_kernel<<<(45 * 4 * 512 + 255) / 256, 256, 0, stream>>>(gcnW, Gh, Gl, 64, 4, 1433, 45);
  pack_kernel<<<(8 * 8 * 512 + 255) / 256, 256, 0, stream>>>(W1, B1h, B1l, 128, 8, 256, 8);
  pack_kernel<<<(4 * 8 * 512 + 255) / 256, 256, 0, stream>>>(W2, B2h, B2l, 128, 8, 128, 4);
  pack_kernel<<<(4 * 90 * 512 + 255) / 256, 256, 0, stream>>>(W3, B3h, B3l, 1433, 90, 128, 4);

  gcn_mfma<<<1024, 384, 0, stream>>>(seq1, seq2, adj1, adj2, Gh, Gl, gcnB, gcnA, h1, h2);
  sink_kernel<<<2048, 256, 0, stream>>>(h1, h2, resc, discW, out, tws);
  dec12_mfma<<<512, 64, 0, stream>>>(h1, B1h, B1l, b1, a1, B2h, B2l, b2, a2, x3);
  dec3_mfma<<<3072, 64, 0, stream>>>(x3, B3h, B3l, b3, a3, out);
  disc_kernel<<<2048, 256, 0, stream>>>(h1, tws, discB, out);
}

// Round 5
// 333.239 us; speedup vs baseline: 1.4246x; 1.2571x over previous
//
#include <hip/hip_runtime.h>
#include <math.h>

#define BB   8192
#define NIN  1433
#define NH   64
#define SUBG 6
#define HID  128

typedef __attribute__((ext_vector_type(8))) short bf16x8;
typedef __attribute__((ext_vector_type(4))) float f32x4;

__device__ __forceinline__ short f2bf(float x) {
  unsigned u = __float_as_uint(x);
  unsigned r = (u + 0x7fffu + ((u >> 16) & 1u)) >> 16;   // RNE
  return (short)r;
}
__device__ __forceinline__ float bf2f(short s) {
  return __uint_as_float(((unsigned)(unsigned short)s) << 16);
}
__device__ __forceinline__ float allred64(float v) {
#pragma unroll
  for (int m = 1; m < 64; m <<= 1) v += __shfl_xor(v, m, 64);
  return v;
}

__device__ __forceinline__ void gload_lds16(const short* g, short* l) {
  __builtin_amdgcn_global_load_lds(
      (const __attribute__((address_space(1))) void*)g,
      (__attribute__((address_space(3))) void*)l, 16, 0, 0);
}

#define WAITV(N)                                            \
  {                                                         \
    asm volatile("s_waitcnt vmcnt(" #N ")" ::: "memory");   \
    __builtin_amdgcn_sched_barrier(0);                      \
  }
#define BARRIER()                                           \
  {                                                         \
    __builtin_amdgcn_s_barrier();                           \
    __builtin_amdgcn_sched_barrier(0);                      \
  }

// ---------------- prep: split W into fragment-major packed bf16 hi/lo ----------------
// dst[((c*NF + nf)*64 + lane)*8 + j] = W[o][k], o = nf*16 + (lane&15),
// k = c*32 + (lane>>4)*8 + j.  Zero-padded outside (Oreal,Kreal).
__global__ void pack_kernel(const float* __restrict__ src, short* __restrict__ hi,
                            short* __restrict__ lo, int Oreal, int NF, int Kreal, int nchunk) {
  int idx = blockIdx.x * 256 + threadIdx.x;
  int total = nchunk * NF * 512;
  if (idx >= total) return;
  int j    = idx & 7;
  int lane = (idx >> 3) & 63;
  int nf   = (idx >> 9) % NF;
  int c    = idx / (NF * 512);
  int o = nf * 16 + (lane & 15);
  int k = c * 32 + ((lane >> 4) << 3) + j;
  float v = (o < Oreal && k < Kreal) ? src[(size_t)o * Kreal + k] : 0.f;
  short h = f2bf(v);
  hi[idx] = h;
  lo[idx] = f2bf(v - bf2f(h));
}

// ---------------- Kernel 1: GCN matmul only (fts = seq @ W^T), split-bf16 MFMA ----------------
// 384 threads (6 waves), wave: 16 rows x 64 cols. Block: 96 rows. grid 1024 ([0,512)=seq1).
// B: LDS ring-4 x 8KB via global_load_lds; A: asm dwordx4, depth-2; counted vmcnt, 1 barrier/chunk.
// NO adjacency combine here (moved to sink) -> minimal LDS -> 4 blocks/CU.
__global__ __launch_bounds__(384, 6) void gcn_mfma(
    const float* __restrict__ seq1, const float* __restrict__ seq2,
    const short* __restrict__ Gh, const short* __restrict__ Gl,
    float* __restrict__ fts1, float* __restrict__ fts2)
{
  __shared__ short sB[4][4096];       // ring-4 slots: [hi 256 pieces][lo 256 pieces] x 16B
  const int tid = threadIdx.x;
  const int sid = blockIdx.x >> 9;
  const int bb  = blockIdx.x & 511;
  const float* __restrict__ seq = sid ? seq2 : seq1;
  float* __restrict__ fout = sid ? fts2 : fts1;
  const int row0 = bb * 96;
  const int w = tid >> 6, lane = tid & 63;
  const int l15 = lane & 15, lg = lane >> 4;

  f32x4 acc[4];
#pragma unroll
  for (int i = 0; i < 4; ++i) acc[i] = (f32x4){0.f, 0.f, 0.f, 0.f};

  const float* aptr = seq + (size_t)(row0 + w * 16 + l15) * NIN;

  // stage B chunk c into slot: exactly 2 global_load_lds per thread (waves 4,5 redundant dup)
  auto STAGE = [&](int c, int slot) {
    short* sb = &sB[slot][0];
    const size_t cb = (size_t)c * 256;
#pragma unroll
    for (int i = 0; i < 2; ++i) {
      const int pb = (w * 128 + i * 64) & 511;      // wave-uniform base piece
      const short* src = (pb < 256) ? (Gh + (cb + pb) * 8 + (size_t)lane * 8)
                                    : (Gl + (cb + (pb - 256)) * 8 + (size_t)lane * 8);
      gload_lds16(src, sb + (pb + lane) * 8);
    }
  };
  // A chunk c: exactly 2 asm dwordx4 per thread (c <= 43 always in-bounds)
  auto ALOAD = [&](int c, f32x4& p, f32x4& q) {
    const float* ad = aptr + c * 32 + lg * 8;
    asm volatile("global_load_dwordx4 %0, %2, off\n\t"
                 "global_load_dwordx4 %1, %2, off offset:16"
                 : "=v"(p), "=v"(q) : "v"(ad));
  };
  auto COMPUTE = [&](int c, const f32x4& p, const f32x4& q) {
    float av[8] = {p[0], p[1], p[2], p[3], q[0], q[1], q[2], q[3]};
    bf16x8 Ah, Al;
#pragma unroll
    for (int j = 0; j < 8; ++j) {
      short h = f2bf(av[j]);
      Ah[j] = h;
      Al[j] = f2bf(av[j] - bf2f(h));
    }
    const short* bs = &sB[c & 3][0];
#pragma unroll
    for (int nf = 0; nf < 4; ++nf) {
      bf16x8 Bh = *(const bf16x8*)(bs + (nf * 64 + lane) * 8);
      bf16x8 Bl = *(const bf16x8*)(bs + 2048 + (nf * 64 + lane) * 8);
      acc[nf] = __builtin_amdgcn_mfma_f32_16x16x32_bf16(Ah, Bh, acc[nf], 0, 0, 0);
      acc[nf] = __builtin_amdgcn_mfma_f32_16x16x32_bf16(Al, Bh, acc[nf], 0, 0, 0);
      acc[nf] = __builtin_amdgcn_mfma_f32_16x16x32_bf16(Ah, Bl, acc[nf], 0, 0, 0);
    }
  };

  f32x4 pa, qa, pb, qb, pc, qc;
  // prologue: groups 0,1 (each group = 2 STAGE + 2 ALOAD instrs per thread)
  STAGE(0, 0); ALOAD(0, pa, qa);
  STAGE(1, 1); ALOAD(1, pb, qb);

  // bodies 0..41 (14 triples): issue group c+2; WAITV(8) -> group c done; barrier; compute c
  for (int cc = 0; cc < 42; cc += 3) {
    STAGE(cc + 2, (cc + 2) & 3); ALOAD(cc + 2, pc, qc);
    WAITV(8); BARRIER();
    COMPUTE(cc, pa, qa);
    STAGE(cc + 3, (cc + 3) & 3); ALOAD(cc + 3, pa, qa);
    WAITV(8); BARRIER();
    COMPUTE(cc + 1, pb, qb);
    STAGE(cc + 4, (cc + 4) & 3); ALOAD(cc + 4, pb, qb);
    WAITV(8); BARRIER();
    COMPUTE(cc + 2, pc, qc);
  }
  // bodies 42, 43 (no further issues): outstanding = groups 42,43
  WAITV(4); BARRIER();
  COMPUTE(42, pa, qa);
  WAITV(0); BARRIER();
  COMPUTE(43, pb, qb);

  // epilogue chunk 44: k = 1408..1439 (guard A; B zero-padded, read from L2)
  {
    const int k0 = 44 * 32 + lg * 8;
    float av[8];
#pragma unroll
    for (int j = 0; j < 8; ++j) {
      int k = k0 + j;
      av[j] = (k < NIN) ? aptr[k] : 0.f;
    }
    bf16x8 Ah, Al;
#pragma unroll
    for (int j = 0; j < 8; ++j) {
      short h = f2bf(av[j]);
      Ah[j] = h;
      Al[j] = f2bf(av[j] - bf2f(h));
    }
#pragma unroll
    for (int nf = 0; nf < 4; ++nf) {
      const size_t off = ((size_t)(44 * 4 + nf) * 64 + lane) * 8;
      bf16x8 Bh = *(const bf16x8*)(Gh + off);
      bf16x8 Bl = *(const bf16x8*)(Gl + off);
      acc[nf] = __builtin_amdgcn_mfma_f32_16x16x32_bf16(Ah, Bh, acc[nf], 0, 0, 0);
      acc[nf] = __builtin_amdgcn_mfma_f32_16x16x32_bf16(Al, Bh, acc[nf], 0, 0, 0);
      acc[nf] = __builtin_amdgcn_mfma_f32_16x16x32_bf16(Ah, Bl, acc[nf], 0, 0, 0);
    }
  }

  // store raw fts (C layout: row = lg*4+j, col = nf*16+l15)
#pragma unroll
  for (int nf = 0; nf < 4; ++nf)
#pragma unroll
    for (int j = 0; j < 4; ++j)
      fout[(size_t)(row0 + w * 16 + lg * 4 + j) * 64 + nf * 16 + l15] = acc[nf][j];
}

// ---------------- Kernel 2: adj-combine + sinkhorn + t = discW @ c + h1 write ----------------
// one wave per batch; lane = feature index
__global__ __launch_bounds__(256) void sink_kernel(
    const float* __restrict__ fts1, const float* __restrict__ fts2,
    const float* __restrict__ adj1, const float* __restrict__ adj2,
    const float* __restrict__ resc, const float* __restrict__ discW,
    const float* __restrict__ bias, const float* __restrict__ aP,
    float* __restrict__ out, float* __restrict__ tws, float* __restrict__ h1w)
{
  const int b = (blockIdx.x << 2) + (threadIdx.x >> 6);
  const int lane = threadIdx.x & 63;
  const float* F1 = fts1 + (size_t)b * 384;
  const float* F2 = fts2 + (size_t)b * 384;
  float f1[6], f2[6];
#pragma unroll
  for (int m = 0; m < 6; ++m) { f1[m] = F1[m * 64 + lane]; f2[m] = F2[m * 64 + lane]; }
  const float bv = bias[lane];
  const float a = aP[0];
  const float* A1 = adj1 + (size_t)b * 36;
  const float* A2 = adj2 + (size_t)b * 36;
  float h1v[6], h2v[6];
#pragma unroll
  for (int n = 0; n < 6; ++n) {
    float o1 = bv, o2 = bv;
#pragma unroll
    for (int m = 0; m < 6; ++m) {
      o1 = fmaf(A1[n * 6 + m], f1[m], o1);
      o2 = fmaf(A2[n * 6 + m], f2[m], o2);
    }
    h1v[n] = (o1 >= 0.f) ? o1 : a * o1;
    h2v[n] = (o2 >= 0.f) ? o2 : a * o2;
  }
  // h1 needed by decoder + discriminator
#pragma unroll
  for (int n = 0; n < 6; ++n) h1w[(size_t)b * 384 + n * 64 + lane] = h1v[n];

  float g1[5], g2[5];
#pragma unroll
  for (int i = 0; i < 4; ++i) { g1[i] = h1v[i]; g2[i] = h2v[i]; }
  g1[4] = h1v[5]; g2[4] = h2v[5];          // swapped row
  const float n1 = h1v[4], n2 = h2v[4];

  {
    float cm = (g1[0] + g1[1] + g1[2] + g1[3] + n1) * 0.2f;
    float t = 0.f;
    const float4* W4 = (const float4*)discW;
#pragma unroll 4
    for (int jq = 0; jq < 16; ++jq) {
      float4 wv = W4[lane * 16 + jq];
      t = fmaf(wv.x, __shfl(cm, 4 * jq, 64), t);
      t = fmaf(wv.y, __shfl(cm, 4 * jq + 1, 64), t);
      t = fmaf(wv.z, __shfl(cm, 4 * jq + 2, 64), t);
      t = fmaf(wv.w, __shfl(cm, 4 * jq + 3, 64), t);
    }
    tws[(size_t)b * 64 + lane] = t;
  }

  float in1[5], in2[5];
#pragma unroll
  for (int i = 0; i < 5; ++i) {
    float s = allred64(g1[i] * g1[i]);
    in1[i] = 1.f / fmaxf(sqrtf(s), 1e-12f);
    s = allred64(g2[i] * g2[i]);
    in2[i] = 1.f / fmaxf(sqrtf(s), 1e-12f);
  }
  float cost[25], P[25];
#pragma unroll
  for (int i = 0; i < 5; ++i)
#pragma unroll
    for (int j = 0; j < 5; ++j) {
      float d = allred64(g1[i] * g2[j]);
      float cv = (1.f - d * in1[i] * in2[j]) * resc[(size_t)b * 25 + i * 5 + j];
      cost[i * 5 + j] = cv;
      P[i * 5 + j] = expf(-20.f * cv);
    }
  float r[5], c[5];
  float rs = 0.f, cs = 0.f;
#pragma unroll
  for (int i = 0; i < 5; ++i) {
    float d = allred64(g1[i] * n2); d = (d <= 0.f) ? 1e-8f : d; r[i] = d; rs += d;
    d = allred64(g2[i] * n1);       d = (d <= 0.f) ? 1e-8f : d; c[i] = d; cs += d;
  }
#pragma unroll
  for (int i = 0; i < 5; ++i) { r[i] = r[i] / rs; c[i] = c[i] / cs; }

  float u[5], v[5];
#pragma unroll
  for (int i = 0; i < 5; ++i) u[i] = 0.2f;
#pragma unroll
  for (int it = 0; it < 5; ++it) {
#pragma unroll
    for (int i = 0; i < 5; ++i) {
      float pv = 0.f;
#pragma unroll
      for (int j = 0; j < 5; ++j) pv = fmaf(P[i * 5 + j], u[j], pv);
      v[i] = r[i] / pv;
    }
#pragma unroll
    for (int i = 0; i < 5; ++i) {
      float pu = 0.f;
#pragma unroll
      for (int j = 0; j < 5; ++j) pu = fmaf(P[j * 5 + i], v[j], pu);
      u[i] = c[i] / pu;
    }
  }
  float S = 0.f;
#pragma unroll
  for (int i = 0; i < 5; ++i)
#pragma unroll
    for (int j = 0; j < 5; ++j)
      S += v[i] * P[i * 5 + j] * u[j] * (1.f - cost[i * 5 + j]);
  if (lane == 0) out[(size_t)b * 1436] = expf(S * 2.5f) * 2.f;
}

// ---------------- Kernel 3a: decoder layers 1+2 (MFMA) -> x3 ----------------
__global__ __launch_bounds__(64) void dec12_mfma(
    const float* __restrict__ h1,
    const short* __restrict__ B1h, const short* __restrict__ B1l,
    const float* __restrict__ b1, const float* __restrict__ a1P,
    const short* __restrict__ B2h, const short* __restrict__ B2l,
    const float* __restrict__ b2, const float* __restrict__ a2P,
    float* __restrict__ x3)
{
  __shared__ float xT[16][132];
  const int lane = threadIdx.x;
  const int l15 = lane & 15, lg = lane >> 4;
  const int r0 = blockIdx.x * 16;

  f32x4 acc[8];
#pragma unroll
  for (int i = 0; i < 8; ++i) acc[i] = (f32x4){0.f, 0.f, 0.f, 0.f};

  // ---- layer 1: K=256, O=128 ----
#pragma unroll
  for (int c = 0; c < 8; ++c) {
    const float* ap = h1 + (size_t)(r0 + l15) * 384 + c * 32 + lg * 8;
    float4 p = *(const float4*)ap;
    float4 q = *(const float4*)(ap + 4);
    float av[8] = {p.x, p.y, p.z, p.w, q.x, q.y, q.z, q.w};
    bf16x8 Ah, Al;
#pragma unroll
    for (int j = 0; j < 8; ++j) { short h = f2bf(av[j]); Ah[j] = h; Al[j] = f2bf(av[j] - bf2f(h)); }
#pragma unroll
    for (int nf = 0; nf < 8; ++nf) {
      size_t off = (((size_t)(c * 8 + nf)) << 9) + (size_t)lane * 8;
      bf16x8 Bh = *(const bf16x8*)(B1h + off);
      bf16x8 Bl = *(const bf16x8*)(B1l + off);
      acc[nf] = __builtin_amdgcn_mfma_f32_16x16x32_bf16(Ah, Bh, acc[nf], 0, 0, 0);
      acc[nf] = __builtin_amdgcn_mfma_f32_16x16x32_bf16(Al, Bh, acc[nf], 0, 0, 0);
      acc[nf] = __builtin_amdgcn_mfma_f32_16x16x32_bf16(Ah, Bl, acc[nf], 0, 0, 0);
    }
  }
  {
    const float a1 = a1P[0];
#pragma unroll
    for (int nf = 0; nf < 8; ++nf) {
      int o = nf * 16 + l15;
      float bv = b1[o];
#pragma unroll
      for (int j = 0; j < 4; ++j) {
        float v = acc[nf][j] + bv;
        xT[lg * 4 + j][o] = (v >= 0.f) ? v : a1 * v;
      }
    }
  }
  __syncthreads();

  // ---- layer 2: K=128, O=128 ----
#pragma unroll
  for (int i = 0; i < 8; ++i) acc[i] = (f32x4){0.f, 0.f, 0.f, 0.f};
#pragma unroll
  for (int c = 0; c < 4; ++c) {
    const float* ap = &xT[l15][c * 32 + lg * 8];
    float4 p = *(const float4*)ap;
    float4 q = *(const float4*)(ap + 4);
    float av[8] = {p.x, p.y, p.z, p.w, q.x, q.y, q.z, q.w};
    bf16x8 Ah, Al;
#pragma unroll
    for (int j = 0; j < 8; ++j) { short h = f2bf(av[j]); Ah[j] = h; Al[j] = f2bf(av[j] - bf2f(h)); }
#pragma unroll
    for (int nf = 0; nf < 8; ++nf) {
      size_t off = (((size_t)(c * 8 + nf)) << 9) + (size_t)lane * 8;
      bf16x8 Bh = *(const bf16x8*)(B2h + off);
      bf16x8 Bl = *(const bf16x8*)(B2l + off);
      acc[nf] = __builtin_amdgcn_mfma_f32_16x16x32_bf16(Ah, Bh, acc[nf], 0, 0, 0);
      acc[nf] = __builtin_amdgcn_mfma_f32_16x16x32_bf16(Al, Bh, acc[nf], 0, 0, 0);
      acc[nf] = __builtin_amdgcn_mfma_f32_16x16x32_bf16(Ah, Bl, acc[nf], 0, 0, 0);
    }
  }
  {
    const float a2 = a2P[0];
#pragma unroll
    for (int nf = 0; nf < 8; ++nf) {
      int o = nf * 16 + l15;
      float bv = b2[o];
#pragma unroll
      for (int j = 0; j < 4; ++j) {
        float v = acc[nf][j] + bv;
        v = (v >= 0.f) ? v : a2 * v;
        x3[(size_t)(r0 + lg * 4 + j) * 128 + o] = v;
      }
    }
  }
}

// ---------------- Kernel 3b: decoder layer 3 (MFMA, nf-split) ----------------
__global__ __launch_bounds__(64) void dec3_mfma(
    const float* __restrict__ x3,
    const short* __restrict__ B3h, const short* __restrict__ B3l,
    const float* __restrict__ b3, const float* __restrict__ a3P,
    float* __restrict__ out)
{
  const int lane = threadIdx.x;
  const int l15 = lane & 15, lg = lane >> 4;
  const int rowblk = blockIdx.x & 511;
  const int nfg = blockIdx.x >> 9;     // 0..5, 15 nf each (90 total)
  const int r0 = rowblk * 16;

  bf16x8 A3h[4], A3l[4];
#pragma unroll
  for (int c = 0; c < 4; ++c) {
    const float* ap = x3 + (size_t)(r0 + l15) * 128 + c * 32 + lg * 8;
    float4 p = *(const float4*)ap;
    float4 q = *(const float4*)(ap + 4);
    float av[8] = {p.x, p.y, p.z, p.w, q.x, q.y, q.z, q.w};
#pragma unroll
    for (int j = 0; j < 8; ++j) {
      short h = f2bf(av[j]); A3h[c][j] = h; A3l[c][j] = f2bf(av[j] - bf2f(h));
    }
  }
  const float a3 = a3P[0];
  for (int t = 0; t < 15; ++t) {
    const int nf = nfg * 15 + t;
    f32x4 acc = (f32x4){0.f, 0.f, 0.f, 0.f};
#pragma unroll
    for (int c = 0; c < 4; ++c) {
      size_t off = (((size_t)(c * 90 + nf)) << 9) + (size_t)lane * 8;
      bf16x8 Bh = *(const bf16x8*)(B3h + off);
      bf16x8 Bl = *(const bf16x8*)(B3l + off);
      acc = __builtin_amdgcn_mfma_f32_16x16x32_bf16(A3h[c], Bh, acc, 0, 0, 0);
      acc = __builtin_amdgcn_mfma_f32_16x16x32_bf16(A3l[c], Bh, acc, 0, 0, 0);
      acc = __builtin_amdgcn_mfma_f32_16x16x32_bf16(A3h[c], Bl, acc, 0, 0, 0);
    }
    const int o = nf * 16 + l15;
    if (o < NIN) {
      float bv = b3[o];
#pragma unroll
      for (int j = 0; j < 4; ++j) {
        float v = acc[j] + bv;
        v = (v >= 0.f) ? v : a3 * v;
        out[(size_t)(r0 + lg * 4 + j) * 1436 + 1 + o] = v;
      }
    }
  }
}

// ---------------- Kernel 4: discriminator logits ----------------
__global__ __launch_bounds__(256) void disc_kernel(
    const float* __restrict__ h1, const float* __restrict__ tws,
    const float* __restrict__ dbP, float* __restrict__ out)
{
  const int b = (blockIdx.x << 2) + (threadIdx.x >> 6);
  const int lane = threadIdx.x & 63;
  float hp = h1[((size_t)b * SUBG + 5) * NH + lane];
  float t0 = tws[(size_t)b * 64 + lane];
  int bp = (b == 0) ? (BB - 2) : (b - 1);
  float tp = tws[(size_t)bp * 64 + lane];
  float s1 = allred64(hp * t0);
  float s2 = allred64(hp * tp);
  if (lane == 0) {
    float db = dbP[0];
    out[(size_t)b * 1436 + 1434] = s1 + db;
    out[(size_t)b * 1436 + 1435] = s2 + db;
  }
}

extern "C" void kernel_launch(void* const* d_in, const int* in_sizes, int n_in,
                              void* d_out, int out_size, void* d_ws, size_t ws_size,
                              hipStream_t stream) {
  (void)in_sizes; (void)n_in; (void)out_size; (void)ws_size;
  const float* seq1  = (const float*)d_in[0];
  const float* seq2  = (const float*)d_in[1];
  const float* adj1  = (const float*)d_in[2];
  const float* adj2  = (const float*)d_in[3];
  const float* resc  = (const float*)d_in[4];
  const float* gcnW  = (const float*)d_in[5];
  const float* gcnB  = (const float*)d_in[6];
  const float* gcnA  = (const float*)d_in[7];
  const float* W1    = (const float*)d_in[8];
  const float* b1    = (const float*)d_in[9];
  const float* a1    = (const float*)d_in[10];
  const float* W2    = (const float*)d_in[11];
  const float* b2    = (const float*)d_in[12];
  const float* a2    = (const float*)d_in[13];
  const float* W3    = (const float*)d_in[14];
  const float* b3    = (const float*)d_in[15];
  const float* a3    = (const float*)d_in[16];
  const float* discW = (const float*)d_in[17];
  const float* discB = (const float*)d_in[18];

  float* fts1 = (float*)d_ws;                     // 49152*64
  float* fts2 = fts1 + (size_t)BB * SUBG * NH;    // 49152*64
  float* h1   = fts2 + (size_t)BB * SUBG * NH;    // 8192*384
  float* tws  = h1  + (size_t)BB * SUBG * NH;     // 8192*64
  float* x3   = tws + (size_t)BB * 64;            // 8192*128
  short* Gh   = (short*)(x3 + (size_t)BB * 128);
  short* Gl   = Gh  + 45 * 4 * 512;
  short* B1h  = Gl  + 45 * 4 * 512;
  short* B1l  = B1h + 8 * 8 * 512;
  short* B2h  = B1l + 8 * 8 * 512;
  short* B2l  = B2h + 4 * 8 * 512;
  short* B3h  = B2l + 4 * 8 * 512;
  short* B3l  = B3h + 4 * 90 * 512;
  float* out  = (float*)d_out;

  pack_kernel<<<(45 * 4 * 512 + 255) / 256, 256, 0, stream>>>(gcnW, Gh, Gl, 64, 4, 1433, 45);
  pack_kernel<<<(8 * 8 * 512 + 255) / 256, 256, 0, stream>>>(W1, B1h, B1l, 128, 8, 256, 8);
  pack_kernel<<<(4 * 8 * 512 + 255) / 256, 256, 0, stream>>>(W2, B2h, B2l, 128, 8, 128, 4);
  pack_kernel<<<(4 * 90 * 512 + 255) / 256, 256, 0, stream>>>(W3, B3h, B3l, 1433, 90, 128, 4);

  gcn_mfma<<<1024, 384, 0, stream>>>(seq1, seq2, Gh, Gl, fts1, fts2);
  sink_kernel<<<2048, 256, 0, stream>>>(fts1, fts2, adj1, adj2, resc, discW, gcnB, gcnA,
                                        out, tws, h1);
  dec12_mfma<<<512, 64, 0, stream>>>(h1, B1h, B1l, b1, a1, B2h, B2l, b2, a2, x3);
  dec3_mfma<<<3072, 64, 0, stream>>>(x3, B3h, B3l, b3, a3, out);
  disc_kernel<<<2048, 256, 0, stream>>>(h1, tws, discB, out);
}